// Round 10
// baseline (785.414 us; speedup 1.0000x reference)
//
#include <hip/hip_runtime.h>
#include <stdint.h>

#define L_LEN 512
#define D_DIM 4096
#define H_NUM 8
#define B_NUM 16
#define TOPK  12

typedef float f32x4 __attribute__((ext_vector_type(4)));

// ---------------------------------------------------------------------------
// Stage A: per-channel circular cross-correlation + top-12 + softmax.
// grid = B*H*64 blocks of 256 threads = 4 waves; ONE channel per 32-lane
// half-wave. Lane m = lane&31 owns taus 16m..16m+15.
// Pipeline (r9 post-mortem: depth-2 needed ~113 live VGPRs under a 128 cap
// -> spill-across-wait corruption): IN-PLACE depth-1. Window = 8-quad
// circular buffer R0..R7 (rotates by 4 quads/step -> even/odd wiring);
// k = K0..K3 overwritten in place. After MAC#j its first window quad and
// k quad are dead -> immediately issue next step's reads into those regs.
// Uniform s_waitcnt lgkmcnt(6) before each MAC completes exactly the two
// reads it needs (DS ops complete in order). Liveness ~75 VGPR -> no
// spills. Slack per read ~3 MAC blocks >> 200cy LDS latency.
// All reads inline-asm ds_read_b128 (r4/r6: hipcc scalarizes C-level LDS
// float4). sched_barrier(0) after every wait (rule #18).
// q layout: 16B group G at phys G + (G>>3): every 8 consecutive lanes
// cover all 8 bank-groups (enumerated for all alignment classes).
// Row pads: qs 580 (rows differ by 1 bank-group), ks 516 (same).
// ---------------------------------------------------------------------------

// physical byte address (within channel row) of logical 16B group G
#define QA(G) (qbase + (((((uint32_t)(G)) & 127u) + ((((uint32_t)(G)) & 127u) >> 3)) << 4))

// 64 FMAs: acc[i] += q[i+t]*k[t], t = 0..3 of k-quad KK_; window quads
// QA_..QE_ hold taus [w, w+20) where w = this quad's t0 offset.
#define MAC4x16(QA_, QB_, QC_, QD_, QE_, KK_) do {                            \
    acc0  = fmaf(QA_.x, KK_.x, acc0);  acc0  = fmaf(QA_.y, KK_.y, acc0);      \
    acc0  = fmaf(QA_.z, KK_.z, acc0);  acc0  = fmaf(QA_.w, KK_.w, acc0);      \
    acc1  = fmaf(QA_.y, KK_.x, acc1);  acc1  = fmaf(QA_.z, KK_.y, acc1);      \
    acc1  = fmaf(QA_.w, KK_.z, acc1);  acc1  = fmaf(QB_.x, KK_.w, acc1);      \
    acc2  = fmaf(QA_.z, KK_.x, acc2);  acc2  = fmaf(QA_.w, KK_.y, acc2);      \
    acc2  = fmaf(QB_.x, KK_.z, acc2);  acc2  = fmaf(QB_.y, KK_.w, acc2);      \
    acc3  = fmaf(QA_.w, KK_.x, acc3);  acc3  = fmaf(QB_.x, KK_.y, acc3);      \
    acc3  = fmaf(QB_.y, KK_.z, acc3);  acc3  = fmaf(QB_.z, KK_.w, acc3);      \
    acc4  = fmaf(QB_.x, KK_.x, acc4);  acc4  = fmaf(QB_.y, KK_.y, acc4);      \
    acc4  = fmaf(QB_.z, KK_.z, acc4);  acc4  = fmaf(QB_.w, KK_.w, acc4);      \
    acc5  = fmaf(QB_.y, KK_.x, acc5);  acc5  = fmaf(QB_.z, KK_.y, acc5);      \
    acc5  = fmaf(QB_.w, KK_.z, acc5);  acc5  = fmaf(QC_.x, KK_.w, acc5);      \
    acc6  = fmaf(QB_.z, KK_.x, acc6);  acc6  = fmaf(QB_.w, KK_.y, acc6);      \
    acc6  = fmaf(QC_.x, KK_.z, acc6);  acc6  = fmaf(QC_.y, KK_.w, acc6);      \
    acc7  = fmaf(QB_.w, KK_.x, acc7);  acc7  = fmaf(QC_.x, KK_.y, acc7);      \
    acc7  = fmaf(QC_.y, KK_.z, acc7);  acc7  = fmaf(QC_.z, KK_.w, acc7);      \
    acc8  = fmaf(QC_.x, KK_.x, acc8);  acc8  = fmaf(QC_.y, KK_.y, acc8);      \
    acc8  = fmaf(QC_.z, KK_.z, acc8);  acc8  = fmaf(QC_.w, KK_.w, acc8);      \
    acc9  = fmaf(QC_.y, KK_.x, acc9);  acc9  = fmaf(QC_.z, KK_.y, acc9);      \
    acc9  = fmaf(QC_.w, KK_.z, acc9);  acc9  = fmaf(QD_.x, KK_.w, acc9);      \
    acc10 = fmaf(QC_.z, KK_.x, acc10); acc10 = fmaf(QC_.w, KK_.y, acc10);     \
    acc10 = fmaf(QD_.x, KK_.z, acc10); acc10 = fmaf(QD_.y, KK_.w, acc10);     \
    acc11 = fmaf(QC_.w, KK_.x, acc11); acc11 = fmaf(QD_.x, KK_.y, acc11);     \
    acc11 = fmaf(QD_.y, KK_.z, acc11); acc11 = fmaf(QD_.z, KK_.w, acc11);     \
    acc12 = fmaf(QD_.x, KK_.x, acc12); acc12 = fmaf(QD_.y, KK_.y, acc12);     \
    acc12 = fmaf(QD_.z, KK_.z, acc12); acc12 = fmaf(QD_.w, KK_.w, acc12);     \
    acc13 = fmaf(QD_.y, KK_.x, acc13); acc13 = fmaf(QD_.z, KK_.y, acc13);     \
    acc13 = fmaf(QD_.w, KK_.z, acc13); acc13 = fmaf(QE_.x, KK_.w, acc13);     \
    acc14 = fmaf(QD_.z, KK_.x, acc14); acc14 = fmaf(QD_.w, KK_.y, acc14);     \
    acc14 = fmaf(QE_.x, KK_.z, acc14); acc14 = fmaf(QE_.y, KK_.w, acc14);     \
    acc15 = fmaf(QD_.w, KK_.x, acc15); acc15 = fmaf(QE_.x, KK_.y, acc15);     \
    acc15 = fmaf(QE_.y, KK_.z, acc15); acc15 = fmaf(QE_.z, KK_.w, acc15);     \
  } while (0)

#define WAITL(N) do {                                                         \
    asm volatile("s_waitcnt lgkmcnt(" #N ")" ::: "memory");                   \
    __builtin_amdgcn_sched_barrier(0);                                        \
  } while (0)

// issue next-step q quad into just-freed QR and next-step k quad into KR.
// k offset: 64 + 16*(quad#) relative to current step's k base (kcur).
#define ISS2(QR, KR, KOFF) do {                                               \
    const uint32_t qa_ = QA(gnext);                                           \
    asm volatile(                                                             \
      "ds_read_b128 %0, %2\n\t"                                               \
      "ds_read_b128 %1, %3 offset:" #KOFF                                     \
      : "=&v"(QR), "=&v"(KR)                                                  \
      : "v"(qa_), "v"(kcur)                                                   \
      : "memory");                                                            \
    ++gnext;                                                                  \
  } while (0)

// even step: logical window quad i lives in R[i]
#define ESTEP do {                                                            \
    WAITL(6); MAC4x16(R0,R1,R2,R3,R4, K0); ISS2(R0, K0, 64);                  \
    WAITL(6); MAC4x16(R1,R2,R3,R4,R5, K1); ISS2(R1, K1, 80);                  \
    WAITL(6); MAC4x16(R2,R3,R4,R5,R6, K2); ISS2(R2, K2, 96);                  \
    WAITL(6); MAC4x16(R3,R4,R5,R6,R7, K3); ISS2(R3, K3, 112);                 \
    kcur += 64;                                                               \
  } while (0)

// odd step: logical window quad i lives in R[(i+4)&7]
#define OSTEP do {                                                            \
    WAITL(6); MAC4x16(R4,R5,R6,R7,R0, K0); ISS2(R4, K0, 64);                  \
    WAITL(6); MAC4x16(R5,R6,R7,R0,R1, K1); ISS2(R5, K1, 80);                  \
    WAITL(6); MAC4x16(R6,R7,R0,R1,R2, K2); ISS2(R6, K2, 96);                  \
    WAITL(6); MAC4x16(R7,R0,R1,R2,R3, K3); ISS2(R7, K3, 112);                 \
    kcur += 64;                                                               \
  } while (0)

// tail step (odd wiring, no issues): drain with decreasing counts
#define TSTEP do {                                                            \
    WAITL(6); MAC4x16(R4,R5,R6,R7,R0, K0);                                    \
    WAITL(4); MAC4x16(R5,R6,R7,R0,R1, K1);                                    \
    WAITL(2); MAC4x16(R6,R7,R0,R1,R2, K2);                                    \
    WAITL(0); MAC4x16(R7,R0,R1,R2,R3, K3);                                    \
  } while (0)

__global__ __launch_bounds__(256, 4) void corr_topk_kernel(
    const float* __restrict__ Q, const float* __restrict__ K,
    float* __restrict__ ws_w, int* __restrict__ ws_i)
{
  __shared__ __align__(16) float qs[8][580];   // 18560 B
  __shared__ __align__(16) float ks[8][516];   // 16512 B  (total 35072)

  const int tid = threadIdx.x;
  const int bid = blockIdx.x;
  // chunked XCD remap: all 64 blocks of one bh on one XCD (L2 line merge)
  const int work = (bid & 7) * 1024 + (bid >> 3);
  const int bh   = work >> 6;
  const int c0   = (work & 63) * 8;

  const size_t base = (size_t)(bh >> 3) * (size_t)(L_LEN * D_DIM)
                    + (size_t)(bh & 7) * 512 + c0;

  // staging
  #pragma unroll
  for (int rep = 0; rep < 4; ++rep) {
    const int idx  = rep * 256 + tid;       // 0..1023
    const int t    = idx >> 1;
    const int half = idx & 1;
    const float4 qv = *(const float4*)(Q + base + (size_t)t * D_DIM + half * 4);
    const float4 kv = *(const float4*)(K + base + (size_t)t * D_DIM + half * 4);
    const int g  = t >> 2;
    const int pw = ((g + (g >> 3)) << 2) | (t & 3);   // padded word index
    const int cb = half * 4;
    const float qa[4] = {qv.x, qv.y, qv.z, qv.w};
    const float ka[4] = {kv.x, kv.y, kv.z, kv.w};
    #pragma unroll
    for (int j = 0; j < 4; ++j) {
      qs[cb + j][pw] = qa[j];
      ks[cb + j][t]  = ka[j];
    }
  }
  __syncthreads();   // drains lgkm: counter starts clean for counted waits

  const int wv   = tid >> 6;
  const int lane = tid & 63;
  const int m    = lane & 31;               // tau index within channel
  const int ch   = wv * 2 + (lane >> 5);    // channel of this half-wave
  const int tau0 = m * 16;
  const int gq   = m * 4;                   // logical group of tau0

  const uint32_t qbase = (uint32_t)(uintptr_t)(&qs[ch][0]);
  uint32_t       kcur  = (uint32_t)(uintptr_t)(&ks[ch][0]);

  float acc0  = 0.f, acc1  = 0.f, acc2  = 0.f, acc3  = 0.f;
  float acc4  = 0.f, acc5  = 0.f, acc6  = 0.f, acc7  = 0.f;
  float acc8  = 0.f, acc9  = 0.f, acc10 = 0.f, acc11 = 0.f;
  float acc12 = 0.f, acc13 = 0.f, acc14 = 0.f, acc15 = 0.f;
  f32x4 R0, R1, R2, R3, R4, R5, R6, R7;
  f32x4 K0, K1, K2, K3;

  // prologue: issue, in this exact order, the 12 reads whose completion
  // order the counted waits rely on: R0..R3 (step-0 first half), then
  // interleaved (R4,K0,R5,K1,R6,K2,R7,K3) = step-0 second half + k(0).
  {
    const uint32_t p0 = QA(gq),     p1 = QA(gq + 1);
    const uint32_t p2 = QA(gq + 2), p3 = QA(gq + 3);
    const uint32_t p4 = QA(gq + 4), p5 = QA(gq + 5);
    const uint32_t p6 = QA(gq + 6), p7 = QA(gq + 7);
    asm volatile(
      "ds_read_b128 %0, %12\n\t"
      "ds_read_b128 %1, %13\n\t"
      "ds_read_b128 %2, %14\n\t"
      "ds_read_b128 %3, %15\n\t"
      "ds_read_b128 %4, %16\n\t"
      "ds_read_b128 %8, %20\n\t"
      "ds_read_b128 %5, %17\n\t"
      "ds_read_b128 %9, %20 offset:16\n\t"
      "ds_read_b128 %6, %18\n\t"
      "ds_read_b128 %10, %20 offset:32\n\t"
      "ds_read_b128 %7, %19\n\t"
      "ds_read_b128 %11, %20 offset:48"
      : "=&v"(R0), "=&v"(R1), "=&v"(R2), "=&v"(R3),
        "=&v"(R4), "=&v"(R5), "=&v"(R6), "=&v"(R7),
        "=&v"(K0), "=&v"(K1), "=&v"(K2), "=&v"(K3)
      : "v"(p0), "v"(p1), "v"(p2), "v"(p3), "v"(p4), "v"(p5), "v"(p6), "v"(p7),
        "v"(kcur)
      : "memory");
  }
  uint32_t gnext = (uint32_t)(gq + 8);

  // steps 0..29: 15 x (even, odd); step 30 even (issuing); step 31 tail
  #pragma unroll 1
  for (int it = 0; it < 15; ++it) {
    ESTEP;
    OSTEP;
  }
  ESTEP;   // step 30
  TSTEP;   // step 31

  float acc[16] = {acc0, acc1, acc2,  acc3,  acc4,  acc5,  acc6,  acc7,
                   acc8, acc9, acc10, acc11, acc12, acc13, acc14, acc15};

  // ---- top-12 via repeated argmax over the 32-lane channel group
  float bv[TOPK]; int bi[TOPK];
  #pragma unroll
  for (int s = 0; s < TOPK; ++s) {
    float lv = acc[0]; int li = 0;
    #pragma unroll
    for (int i = 1; i < 16; ++i) if (acc[i] > lv) { lv = acc[i]; li = i; }
    int gi = tau0 + li;
    #pragma unroll
    for (int off = 16; off >= 1; off >>= 1) {
      const float ov = __shfl_xor(lv, off, 32);
      const int   oi = __shfl_xor(gi, off, 32);
      if (ov > lv || (ov == lv && oi < gi)) { lv = ov; gi = oi; }
    }
    bv[s] = lv; bi[s] = gi;
    const int slot = gi - tau0;
    #pragma unroll
    for (int i = 0; i < 16; ++i) acc[i] = (slot == i) ? -3.4e38f : acc[i];
  }

  float e[TOPK]; float sum = 0.f;
  #pragma unroll
  for (int s = 0; s < TOPK; ++s) { e[s] = expf(bv[s] - bv[0]); sum += e[s]; }
  const float inv = 1.f / sum;

  if (m == 0) {
    const int g = (bh * 512 + c0 + ch) * TOPK;
    #pragma unroll
    for (int s = 0; s < TOPK; ++s) { ws_w[g + s] = e[s] * inv; ws_i[g + s] = bi[s]; }
  }
}

// ---------------------------------------------------------------------------
// Stage B (verbatim passing version): block = (b, 32-column window of D),
// 512 threads, vs staged in descending quarters (r = min(r0+t,511) >= t ->
// later stagings write strictly lower rows than any concurrent reader;
// 1 barrier/phase; next quarter's loads issued before the barrier, raw
// s_barrier keeps them in flight). LDS = 65536 B exactly.
// ---------------------------------------------------------------------------
__global__ __launch_bounds__(512, 4) void gather_kernel(
    const float* __restrict__ V, const float* __restrict__ ws_w,
    const int* __restrict__ ws_i, float* __restrict__ out)
{
  __shared__ __align__(16) float vs[512][32];   // 65536 B

  const int tid = threadIdx.x;
  const int bid = blockIdx.x;
  const int work = (bid & 7) * 256 + (bid >> 3);   // chunked XCD remap
  const int b  = work >> 7;
  const int dg = work & 127;
  const int d0 = dg * 32;
  const int h  = d0 >> 9;
  const int c0 = d0 & 511;

  const size_t vcol = (size_t)b * (size_t)(L_LEN * D_DIM) + d0;

  const int cl   = tid & 31;
  const int tsub = tid >> 5;              // 0..15

  float4 stga, stgb;
  const int e0 = tid, e1 = 512 + tid;
  const int ra0 = e0 >> 3, qa0 = (e0 & 7) * 4;   // rows 0..63 of quarter
  const int rb0 = e1 >> 3, qb0 = (e1 & 7) * 4;   // rows 64..127 of quarter

  // prologue: issue loads for phase 3 (rows 384..511)
  stga = *(const float4*)(V + vcol + (size_t)(384 + ra0) * D_DIM + qa0);
  stgb = *(const float4*)(V + vcol + (size_t)(384 + rb0) * D_DIM + qb0);

  const int g = ((b * 8 + h) * 512 + c0 + cl) * TOPK;
  float w[TOPK]; int r0[TOPK];
  #pragma unroll
  for (int s = 0; s < TOPK; ++s) { w[s] = ws_w[g + s]; r0[s] = ws_i[g + s]; }

  const size_t ob = vcol + cl;

  #pragma unroll 1
  for (int ph = 3; ph >= 0; --ph) {
    *(float4*)(&vs[ph * 128 + ra0][qa0]) = stga;
    *(float4*)(&vs[ph * 128 + rb0][qb0]) = stgb;
    if (ph > 0) {  // issue next quarter early; in flight across the barrier
      stga = *(const float4*)(V + vcol + (size_t)((ph - 1) * 128 + ra0) * D_DIM + qa0);
      stgb = *(const float4*)(V + vcol + (size_t)((ph - 1) * 128 + rb0) * D_DIM + qb0);
    }
    asm volatile("s_waitcnt lgkmcnt(0)" ::: "memory");
    __builtin_amdgcn_s_barrier();
    asm volatile("" ::: "memory");

    // compute outputs t in [ph*128, (ph+1)*128)
    #pragma unroll
    for (int k8 = 0; k8 < 8; ++k8) {
      const int t = ph * 128 + (k8 << 4) + tsub;
      float a = 0.f;
      #pragma unroll
      for (int s = 0; s < TOPK; ++s) {
        int r = r0[s] + t;
        r = r > (L_LEN - 1) ? (L_LEN - 1) : r;
        a = fmaf(w[s], vs[r][cl], a);       // bank = cl: scatter-immune
      }
      out[ob + (size_t)t * D_DIM] = a;
    }
  }
}

extern "C" void kernel_launch(void* const* d_in, const int* in_sizes, int n_in,
                              void* d_out, int out_size, void* d_ws, size_t ws_size,
                              hipStream_t stream)
{
  const float* Q = (const float*)d_in[0];
  const float* K = (const float*)d_in[1];
  const float* V = (const float*)d_in[2];
  float* out = (float*)d_out;

  float* ws_w = (float*)d_ws;
  int*   ws_i = (int*)((char*)d_ws + (size_t)B_NUM * H_NUM * 512 * TOPK * sizeof(float));

  corr_topk_kernel<<<dim3(B_NUM * H_NUM * 64), dim3(256), 0, stream>>>(Q, K, ws_w, ws_i);
  gather_kernel<<<dim3(B_NUM * H_NUM * 16), dim3(512), 0, stream>>>(V, ws_w, ws_i, out);
}